// Round 2
// baseline (302.931 us; speedup 1.0000x reference)
//
#include <hip/hip_runtime.h>

// LTC cell: B=1024, I=128, N=256, 6 unfolds.
// Round-2 design: lane = batch. v-values live in VGPRs (loaded coalesced from
// a transposed vT[i][b]); synapse params are wave-uniform -> scalar (SMEM)
// loads. Hot loop is pure VALU: mul, sub, exp2, add, rcp, 2x fmac per term.
// No LDS / no VMEM in the inner loop. 512 blocks x 512 thr = 2 blocks/CU,
// 4 waves/SIMD.

#define LOG2E 1.44269504088896340f

constexpr int Bn = 1024;
constexpr int In = 128;
constexpr int Nn = 256;
constexpr int UNFOLDS = 6;

#if __has_builtin(__builtin_amdgcn_exp2f)
#define EXP2F(x) __builtin_amdgcn_exp2f(x)
#else
#define EXP2F(x) __exp2f(x)
#endif
#if __has_builtin(__builtin_amdgcn_rcpf)
#define RCPF(x) __builtin_amdgcn_rcpf(x)
#else
#define RCPF(x) (1.0f / (x))
#endif

// ---------------------------------------------------------------------------
// Pack + transpose kernel:
//   PrecT[n*256+i] = {sig*log2e, sig*mu*log2e, W, W*erev}  (from [i][n] arrays)
//   PsenT[n*128+i] = same for sensory params
//   vT0[i*1024+b]  = state[b*256+i]      (transposed state)
//   inT[i*1024+b]  = inputs[b*128+i]     (transposed inputs)
// ---------------------------------------------------------------------------
__global__ __launch_bounds__(256) void pack_kernel(
    const float* __restrict__ mu, const float* __restrict__ sigma,
    const float* __restrict__ W, const float* __restrict__ erev,
    const float* __restrict__ smu, const float* __restrict__ ssigma,
    const float* __restrict__ sW, const float* __restrict__ serev,
    const float* __restrict__ state, const float* __restrict__ inputs,
    float4* __restrict__ PrecT, float4* __restrict__ PsenT,
    float* __restrict__ vT0, float* __restrict__ inT) {
    int idx = blockIdx.x * 256 + threadIdx.x;
    if (idx < Nn * Nn) {  // PrecT: n = idx>>8, i = idx&255
        int n = idx >> 8, i = idx & 255;
        int src = i * Nn + n;
        float s = sigma[src], m = mu[src], w = W[src], e = erev[src];
        PrecT[idx] = make_float4(s * LOG2E, s * m * LOG2E, w, w * e);
        return;
    }
    int j = idx - Nn * Nn;
    if (j < In * Nn) {  // PsenT: n = j>>7, i = j&127
        int n = j >> 7, i = j & 127;
        int src = i * Nn + n;
        float s = ssigma[src], m = smu[src], w = sW[src], e = serev[src];
        PsenT[j] = make_float4(s * LOG2E, s * m * LOG2E, w, w * e);
        return;
    }
    int k = j - In * Nn;
    if (k < Nn * Bn) {  // vT0: i = k>>10, b = k&1023
        int i = k >> 10, b = k & 1023;
        vT0[k] = state[b * Nn + i];
        return;
    }
    int l = k - Nn * Bn;
    if (l < In * Bn) {  // inT: i = l>>10, b = l&1023
        int i = l >> 10, b = l & 1023;
        inT[l] = inputs[b * In + i];
    }
}

// ---------------------------------------------------------------------------
// Sensory kernel: sensT[n*1024+b] = (sum_i sW*sig*serev, sum_i sW*sig).
// Block = 512 thr = 8 waves; wave w owns i-slice [w*16, w*16+16).
// Grid = 16 b-groups x 32 n-groups (n-range 8) = 512 blocks.
// ---------------------------------------------------------------------------
__global__ __launch_bounds__(512) void sensory_kernel(
    const float* __restrict__ inT, const float* __restrict__ input_w,
    const float* __restrict__ input_b, const float4* __restrict__ PsenT,
    float2* __restrict__ sensT) {
    __shared__ float2 part[8][8][64];  // [slice][n_l][b] = 32 KB
    const int tid = threadIdx.x, w = tid >> 6, lane = tid & 63;
    const int b0 = (blockIdx.x >> 5) * 64;
    const int n0 = (blockIdx.x & 31) * 8;
    const int i0 = w * 16;

    float xr[16];
#pragma unroll
    for (int j = 0; j < 16; ++j)
        xr[j] = inT[(i0 + j) * Bn + b0 + lane] * input_w[i0 + j] + input_b[i0 + j];

    for (int nl = 0; nl < 8; ++nl) {
        const float4* __restrict__ p = PsenT + (n0 + nl) * In + i0;  // uniform
        float num = 0.f, den = 0.f;
#pragma unroll
        for (int j = 0; j < 16; ++j) {
            float4 q = p[j];  // wave-uniform -> s_load
            float t = q.y - q.x * xr[j];
            float r = RCPF(1.0f + EXP2F(t));
            den += q.z * r;
            num += q.w * r;
        }
        part[w][nl][lane] = make_float2(num, den);
    }
    __syncthreads();
    // 512 (n_l, b) pairs, one per thread
    const int nl = tid >> 6, b = tid & 63;
    float wn = 0.f, wd = 0.f;
#pragma unroll
    for (int s = 0; s < 8; ++s) {
        float2 v = part[s][nl][b];
        wn += v.x;
        wd += v.y;
    }
    sensT[(n0 + nl) * Bn + b0 + b] = make_float2(wn, wd);
}

// ---------------------------------------------------------------------------
// Step kernel: one unfold. Block = 512 thr = 8 waves; wave w owns i-slice
// [w*32, w*32+32) held in 32 VGPRs. Grid = 16 b-groups x 32 n-groups = 512.
// Weights via wave-uniform (scalar) loads; inner loop pure VALU.
// ---------------------------------------------------------------------------
template <bool LAST>
__global__ __launch_bounds__(512) void step_kernel(
    const float* __restrict__ vT, const float4* __restrict__ PrecT,
    const float2* __restrict__ sensT, const float* __restrict__ vleak,
    const float* __restrict__ gleak, const float* __restrict__ cmt,
    float* __restrict__ vnextT, float* __restrict__ out) {
    __shared__ float2 part[8][8][64];  // [slice][n_l][b] = 32 KB
    const int tid = threadIdx.x, w = tid >> 6, lane = tid & 63;
    const int b0 = (blockIdx.x >> 5) * 64;
    const int n0 = (blockIdx.x & 31) * 8;
    const int i0 = w * 32;

    float vr[32];
#pragma unroll
    for (int j = 0; j < 32; ++j)
        vr[j] = vT[(i0 + j) * Bn + b0 + lane];  // coalesced

    for (int nl = 0; nl < 8; ++nl) {
        const float4* __restrict__ p = PrecT + (n0 + nl) * Nn + i0;  // uniform
        float num = 0.f, den = 0.f;
#pragma unroll
        for (int j = 0; j < 32; ++j) {
            float4 q = p[j];  // wave-uniform -> s_load (scalar pipe)
            float t = q.y - q.x * vr[j];
            float r = RCPF(1.0f + EXP2F(t));
            den += q.z * r;
            num += q.w * r;
        }
        part[w][nl][lane] = make_float2(num, den);
    }
    __syncthreads();

    // Epilogue: 512 (n_l, b) pairs, one per thread. n_l wave-uniform.
    const int nl = tid >> 6, b = tid & 63;
    const int n = n0 + nl, bg = b0 + b;
    float wn = 0.f, wd = 0.f;
#pragma unroll
    for (int s = 0; s < 8; ++s) {
        float2 v = part[s][nl][b];
        wn += v.x;
        wd += v.y;
    }
    float2 sv = sensT[n * Bn + bg];        // coalesced
    float g = gleak[n], c = cmt[n], vl = vleak[n];  // wave-uniform -> scalar
    float vp = vT[n * Bn + bg];            // coalesced
    float res = (c * vp + g * vl + wn + sv.x) / (c + g + wd + sv.y);
    if (LAST)
        out[bg * Nn + n] = res;            // final transpose-back (1 MB, once)
    else
        vnextT[n * Bn + bg] = res;         // coalesced
}

// ---------------------------------------------------------------------------
extern "C" void kernel_launch(void* const* d_in, const int* in_sizes, int n_in,
                              void* d_out, int out_size, void* d_ws, size_t ws_size,
                              hipStream_t stream) {
    const float* inputs   = (const float*)d_in[0];
    const float* state    = (const float*)d_in[1];
    const float* input_w  = (const float*)d_in[2];
    const float* input_b  = (const float*)d_in[3];
    const float* smu      = (const float*)d_in[4];
    const float* ssigma   = (const float*)d_in[5];
    const float* sW       = (const float*)d_in[6];
    const float* serev    = (const float*)d_in[7];
    const float* mu       = (const float*)d_in[8];
    const float* sigma    = (const float*)d_in[9];
    const float* W        = (const float*)d_in[10];
    const float* erev     = (const float*)d_in[11];
    const float* vleak    = (const float*)d_in[12];
    const float* gleak    = (const float*)d_in[13];
    const float* cmt      = (const float*)d_in[14];
    float* out = (float*)d_out;

    // Workspace layout (~6 MiB total)
    char* ws = (char*)d_ws;
    float4* PrecT = (float4*)ws;                          // 1 MiB
    float4* PsenT = (float4*)(ws + (1u << 20));           // 512 KiB
    float2* sensT = (float2*)(ws + (1u << 20) + (512u << 10));          // 2 MiB
    float*  inT   = (float*)(ws + (3u << 20) + (512u << 10));           // 512 KiB
    float*  vTA   = (float*)(ws + (4u << 20));            // 1 MiB
    float*  vTB   = (float*)(ws + (5u << 20));            // 1 MiB

    const int pack_threads = Nn * Nn + In * Nn + Nn * Bn + In * Bn;  // 491520
    pack_kernel<<<(pack_threads + 255) / 256, 256, 0, stream>>>(
        mu, sigma, W, erev, smu, ssigma, sW, serev, state, inputs,
        PrecT, PsenT, vTA, inT);

    sensory_kernel<<<512, 512, 0, stream>>>(inT, input_w, input_b, PsenT, sensT);

    const float* cur = vTA;
    for (int s = 0; s < UNFOLDS; ++s) {
        float* nxt = (s & 1) ? vTA : vTB;
        if (s == UNFOLDS - 1)
            step_kernel<true><<<512, 512, 0, stream>>>(
                cur, PrecT, sensT, vleak, gleak, cmt, nullptr, out);
        else
            step_kernel<false><<<512, 512, 0, stream>>>(
                cur, PrecT, sensT, vleak, gleak, cmt, nxt, nullptr);
        cur = nxt;
    }
}

// Round 3
// 202.087 us; speedup vs baseline: 1.4990x; 1.4990x over previous
//
#include <hip/hip_runtime.h>

// LTC cell: B=1024, I=128, N=256, 6 unfolds. Round 3.
// lane = n (weights are coalesced per-lane dwordx4 loads, no uniformity bet).
// v broadcast from LDS as [i][4bb] float4 -> ONE ds_read_b128 per i.
// Block 256 = 64 n-lanes x 4 i-slices, bb=4 batches/thread, grid 1024
// -> 4 blocks/CU, 4 waves/SIMD. All tensors natural [b][n] layout.

#define LOG2E 1.44269504088896340f

constexpr int Bn = 1024;
constexpr int In = 128;
constexpr int Nn = 256;
constexpr int UNFOLDS = 6;

#if __has_builtin(__builtin_amdgcn_exp2f)
#define EXP2F(x) __builtin_amdgcn_exp2f(x)
#else
#define EXP2F(x) __exp2f(x)
#endif
#if __has_builtin(__builtin_amdgcn_rcpf)
#define RCPF(x) __builtin_amdgcn_rcpf(x)
#else
#define RCPF(x) (1.0f / (x))
#endif

// ---------------------------------------------------------------------------
// Pack: Prec[i*N+n] = {sigma*log2e, sigma*mu*log2e, W, W*erev}; same for Psen.
// sigmoid(sigma*(v-mu)) = 1/(1 + exp2(B - A*v)), A=sigma*log2e, B=sigma*mu*log2e.
// ---------------------------------------------------------------------------
__global__ __launch_bounds__(256) void pack_kernel(
    const float* __restrict__ mu, const float* __restrict__ sigma,
    const float* __restrict__ W, const float* __restrict__ erev,
    const float* __restrict__ smu, const float* __restrict__ ssigma,
    const float* __restrict__ sW, const float* __restrict__ serev,
    float4* __restrict__ Prec, float4* __restrict__ Psen) {
    int idx = blockIdx.x * 256 + threadIdx.x;
    if (idx < Nn * Nn) {
        float s = sigma[idx], m = mu[idx], w = W[idx], e = erev[idx];
        Prec[idx] = make_float4(s * LOG2E, s * m * LOG2E, w, w * e);
        return;
    }
    int j = idx - Nn * Nn;
    if (j < In * Nn) {
        float s = ssigma[j], m = smu[j], w = sW[j], e = serev[j];
        Psen[j] = make_float4(s * LOG2E, s * m * LOG2E, w, w * e);
    }
}

// ---------------------------------------------------------------------------
// Sensory: sens[b*N+n] = (sum_i sW*sig*serev, sum_i sW*sig).
// Block 256 = 64n x 4 i-slices (32 i each), bb=4. Grid = 256 b-tiles x 4 n = 1024.
// ---------------------------------------------------------------------------
__global__ __launch_bounds__(256) void sensory_kernel(
    const float* __restrict__ inputs, const float* __restrict__ input_w,
    const float* __restrict__ input_b, const float4* __restrict__ Psen,
    float2* __restrict__ sens) {
    __shared__ float4 xs[In];            // [i] -> 4 batches packed, 2 KB
    __shared__ float2 part[4][4][64];    // [slice][bb][n_l], 8 KB

    const int tid = threadIdx.x;
    const int b0 = (blockIdx.x >> 2) * 4;
    const int n0 = (blockIdx.x & 3) * 64;

    for (int k = tid; k < 4 * In; k += 256) {
        int i = k >> 2, bb = k & 3;
        ((float*)xs)[i * 4 + bb] =
            inputs[(b0 + bb) * In + i] * input_w[i] + input_b[i];
    }
    __syncthreads();

    const int n_l = tid & 63;
    const int sl = tid >> 6;
    const float4* __restrict__ pp = Psen + n0 + n_l;

    float num[4] = {0.f, 0.f, 0.f, 0.f};
    float den[4] = {0.f, 0.f, 0.f, 0.f};
#pragma unroll 4
    for (int i = sl * 32; i < sl * 32 + 32; ++i) {
        float4 p = pp[i * Nn];   // coalesced dwordx4 across n-lanes
        float4 v = xs[i];        // single ds_read_b128 broadcast
#pragma unroll
        for (int bb = 0; bb < 4; ++bb) {
            float vb = (bb == 0) ? v.x : (bb == 1) ? v.y : (bb == 2) ? v.z : v.w;
            float r = RCPF(1.0f + EXP2F(fmaf(-p.x, vb, p.y)));
            den[bb] += p.z * r;
            num[bb] += p.w * r;
        }
    }
#pragma unroll
    for (int bb = 0; bb < 4; ++bb)
        part[sl][bb][n_l] = make_float2(num[bb], den[bb]);
    __syncthreads();

    const int bb = tid >> 6, nl2 = tid & 63;
    float wn = 0.f, wd = 0.f;
#pragma unroll
    for (int s = 0; s < 4; ++s) {
        float2 v = part[s][bb][nl2];
        wn += v.x;
        wd += v.y;
    }
    sens[(b0 + bb) * Nn + n0 + nl2] = make_float2(wn, wd);
}

// ---------------------------------------------------------------------------
// Step: one unfold. Block 256 = 64n x 4 i-slices (64 i each), bb=4.
// Grid = 256 b-tiles x 4 n-tiles = 1024 blocks -> 4 blocks/CU, 4 waves/SIMD.
// ---------------------------------------------------------------------------
__global__ __launch_bounds__(256) void step_kernel(
    const float* __restrict__ vcur, const float4* __restrict__ Prec,
    const float2* __restrict__ sens, const float* __restrict__ vleak,
    const float* __restrict__ gleak, const float* __restrict__ cmt,
    float* __restrict__ vnext) {
    __shared__ float4 vt[Nn];            // [i] -> 4 batches packed, 4 KB
    __shared__ float2 part[4][4][64];    // [slice][bb][n_l], 8 KB

    const int tid = threadIdx.x;
    const int b0 = (blockIdx.x >> 2) * 4;
    const int n0 = (blockIdx.x & 3) * 64;

    for (int k = tid; k < 4 * Nn; k += 256) {
        int i = k >> 2, bb = k & 3;
        ((float*)vt)[i * 4 + bb] = vcur[(b0 + bb) * Nn + i];
    }
    __syncthreads();

    const int n_l = tid & 63;
    const int sl = tid >> 6;
    const float4* __restrict__ pp = Prec + n0 + n_l;

    float num[4] = {0.f, 0.f, 0.f, 0.f};
    float den[4] = {0.f, 0.f, 0.f, 0.f};
#pragma unroll 4
    for (int i = sl * 64; i < sl * 64 + 64; ++i) {
        float4 p = pp[i * Nn];   // coalesced dwordx4 across n-lanes
        float4 v = vt[i];        // single ds_read_b128 broadcast
#pragma unroll
        for (int bb = 0; bb < 4; ++bb) {
            float vb = (bb == 0) ? v.x : (bb == 1) ? v.y : (bb == 2) ? v.z : v.w;
            float r = RCPF(1.0f + EXP2F(fmaf(-p.x, vb, p.y)));
            den[bb] += p.z * r;
            num[bb] += p.w * r;
        }
    }
#pragma unroll
    for (int bb = 0; bb < 4; ++bb)
        part[sl][bb][n_l] = make_float2(num[bb], den[bb]);
    __syncthreads();

    // Epilogue: one (bb, n_l) output per thread.
    const int bb = tid >> 6, nl2 = tid & 63;
    const int n = n0 + nl2, b = b0 + bb;
    float wn = 0.f, wd = 0.f;
#pragma unroll
    for (int s = 0; s < 4; ++s) {
        float2 v = part[s][bb][nl2];
        wn += v.x;
        wd += v.y;
    }
    float2 sv = sens[b * Nn + n];
    float g = gleak[n], c = cmt[n], vl = vleak[n];
    float vp = vcur[b * Nn + n];
    vnext[b * Nn + n] = (c * vp + g * vl + wn + sv.x) / (c + g + wd + sv.y);
}

// ---------------------------------------------------------------------------
extern "C" void kernel_launch(void* const* d_in, const int* in_sizes, int n_in,
                              void* d_out, int out_size, void* d_ws, size_t ws_size,
                              hipStream_t stream) {
    const float* inputs   = (const float*)d_in[0];
    const float* state    = (const float*)d_in[1];
    const float* input_w  = (const float*)d_in[2];
    const float* input_b  = (const float*)d_in[3];
    const float* smu      = (const float*)d_in[4];
    const float* ssigma   = (const float*)d_in[5];
    const float* sW       = (const float*)d_in[6];
    const float* serev    = (const float*)d_in[7];
    const float* mu       = (const float*)d_in[8];
    const float* sigma    = (const float*)d_in[9];
    const float* W        = (const float*)d_in[10];
    const float* erev     = (const float*)d_in[11];
    const float* vleak    = (const float*)d_in[12];
    const float* gleak    = (const float*)d_in[13];
    const float* cmt      = (const float*)d_in[14];
    float* out = (float*)d_out;

    // Workspace: Prec 1 MiB | Psen 512 KiB | sens 2 MiB | vA 1 MiB | vB 1 MiB
    char* ws = (char*)d_ws;
    float4* Prec = (float4*)ws;
    float4* Psen = (float4*)(ws + (1u << 20));
    float2* sens = (float2*)(ws + (1u << 20) + (512u << 10));
    float*  vA   = (float*)(ws + (3u << 20) + (512u << 10));
    float*  vB   = (float*)(ws + (4u << 20) + (512u << 10));

    pack_kernel<<<(Nn * Nn + In * Nn + 255) / 256, 256, 0, stream>>>(
        mu, sigma, W, erev, smu, ssigma, sW, serev, Prec, Psen);

    sensory_kernel<<<1024, 256, 0, stream>>>(inputs, input_w, input_b, Psen, sens);

    const float* cur = state;
    for (int s = 0; s < UNFOLDS; ++s) {
        float* nxt = (s == UNFOLDS - 1) ? out : ((s & 1) ? vB : vA);
        step_kernel<<<1024, 256, 0, stream>>>(cur, Prec, sens, vleak, gleak, cmt, nxt);
        cur = nxt;
    }
}

// Round 4
// 180.409 us; speedup vs baseline: 1.6791x; 1.1202x over previous
//
#include <hip/hip_runtime.h>

// LTC cell: B=1024, I=128, N=256, 6 unfolds. Round 4: FULLY FUSED recurrence.
// Each block owns 4 batches x all 256 neurons -> no cross-block deps across
// unfolds; the whole 6-step recurrence runs in one kernel with __syncthreads.
// Block 1024 thr = (n = tid&255) x (ih = tid>>8, 4 i-slices). ih is
// wave-uniform -> vt[i] is a ds_read_b128 broadcast; n consecutive in wave ->
// weight loads are coalesced dwordx4. Grid 256 = 1 block/CU, 4 waves/SIMD.
// v_pre, sensory sums, leak params all live in registers of thread (bb=ih, n).

#define LOG2E 1.44269504088896340f

constexpr int Bn = 1024;
constexpr int In = 128;
constexpr int Nn = 256;
constexpr int UNFOLDS = 6;

#if __has_builtin(__builtin_amdgcn_exp2f)
#define EXP2F(x) __builtin_amdgcn_exp2f(x)
#else
#define EXP2F(x) __exp2f(x)
#endif
#if __has_builtin(__builtin_amdgcn_rcpf)
#define RCPF(x) __builtin_amdgcn_rcpf(x)
#else
#define RCPF(x) (1.0f / (x))
#endif

// ---------------------------------------------------------------------------
// Pack: Prec[i*N+n] = {sigma*log2e, sigma*mu*log2e, W, W*erev}; same for Psen.
// sigmoid(sigma*(v-mu)) = 1/(1 + exp2(B - A*v)), A=sigma*log2e, B=sigma*mu*log2e.
// ---------------------------------------------------------------------------
__global__ __launch_bounds__(256) void pack_kernel(
    const float* __restrict__ mu, const float* __restrict__ sigma,
    const float* __restrict__ W, const float* __restrict__ erev,
    const float* __restrict__ smu, const float* __restrict__ ssigma,
    const float* __restrict__ sW, const float* __restrict__ serev,
    float4* __restrict__ Prec, float4* __restrict__ Psen) {
    int idx = blockIdx.x * 256 + threadIdx.x;
    if (idx < Nn * Nn) {
        float s = sigma[idx], m = mu[idx], w = W[idx], e = erev[idx];
        Prec[idx] = make_float4(s * LOG2E, s * m * LOG2E, w, w * e);
        return;
    }
    int j = idx - Nn * Nn;
    if (j < In * Nn) {
        float s = ssigma[j], m = smu[j], w = sW[j], e = serev[j];
        Psen[j] = make_float4(s * LOG2E, s * m * LOG2E, w, w * e);
    }
}

// ---------------------------------------------------------------------------
// Fused LTC kernel: sensory + 6 unfolds. Grid = 256 blocks x 1024 threads.
// ---------------------------------------------------------------------------
__global__ __launch_bounds__(1024, 1) void ltc_fused_kernel(
    const float* __restrict__ inputs, const float* __restrict__ state,
    const float* __restrict__ input_w, const float* __restrict__ input_b,
    const float4* __restrict__ Psen, const float4* __restrict__ Prec,
    const float* __restrict__ vleak, const float* __restrict__ gleak,
    const float* __restrict__ cmt, float* __restrict__ out) {
    __shared__ float4 vt[Nn];            // [i] -> 4 batches packed, 4 KB
    __shared__ float2 part[4][4][Nn];    // [ih][bb][n], 32 KB
    __shared__ float4 xs[In];            // sensory x, [i] -> 4 batches, 2 KB

    const int tid = threadIdx.x;
    const int b0 = blockIdx.x * 4;
    const int n = tid & 255;
    const int ih = tid >> 8;  // 0..3 : i-slice for compute, bb for reduce

    // ---- fill: v state (this thread's (bb=ih, n) value) + sensory x ----
    float vp = state[(b0 + ih) * Nn + n];      // coalesced
    ((float*)vt)[n * 4 + ih] = vp;
    if (tid < 4 * In) {
        int i = tid & 127, bb = tid >> 7;      // bb in 0..3
        ((float*)xs)[i * 4 + bb] =
            inputs[(b0 + bb) * In + i] * input_w[i] + input_b[i];
    }
    // leak params for this thread's n (wavefront-coalesced loads)
    const float g = gleak[n], c = cmt[n];
    const float gvl = g * vleak[n];
    __syncthreads();

    // ---- sensory sums (i = 0..127, slice 32 per ih) ----
    float sens_n, sens_d;
    {
        float num[4] = {0.f, 0.f, 0.f, 0.f};
        float den[4] = {0.f, 0.f, 0.f, 0.f};
        const float4* __restrict__ pp = Psen + n;
#pragma unroll 8
        for (int i = ih * 32; i < ih * 32 + 32; ++i) {
            float4 p = pp[i * Nn];   // coalesced dwordx4
            float4 v = xs[i];        // b128 broadcast (ih wave-uniform)
#pragma unroll
            for (int bb = 0; bb < 4; ++bb) {
                float vb = (bb == 0) ? v.x : (bb == 1) ? v.y : (bb == 2) ? v.z : v.w;
                float r = RCPF(1.0f + EXP2F(fmaf(-p.x, vb, p.y)));
                den[bb] += p.z * r;
                num[bb] += p.w * r;
            }
        }
#pragma unroll
        for (int bb = 0; bb < 4; ++bb)
            part[ih][bb][n] = make_float2(num[bb], den[bb]);
        __syncthreads();
        float wn = 0.f, wd = 0.f;
#pragma unroll
        for (int s = 0; s < 4; ++s) {
            float2 v = part[s][ih][n];  // this thread's bb == ih
            wn += v.x;
            wd += v.y;
        }
        sens_n = wn;
        sens_d = wd;
    }

    // ---- 6 unfolds ----
    const float4* __restrict__ pp = Prec + n;
    for (int s = 0; s < UNFOLDS; ++s) {
        __syncthreads();  // vt writes from prev step visible; part reusable
        float num[4] = {0.f, 0.f, 0.f, 0.f};
        float den[4] = {0.f, 0.f, 0.f, 0.f};
#pragma unroll 8
        for (int i = ih * 64; i < ih * 64 + 64; ++i) {
            float4 p = pp[i * Nn];   // coalesced dwordx4 (L2-resident stream)
            float4 v = vt[i];        // b128 broadcast
#pragma unroll
            for (int bb = 0; bb < 4; ++bb) {
                float vb = (bb == 0) ? v.x : (bb == 1) ? v.y : (bb == 2) ? v.z : v.w;
                float r = RCPF(1.0f + EXP2F(fmaf(-p.x, vb, p.y)));
                den[bb] += p.z * r;
                num[bb] += p.w * r;
            }
        }
#pragma unroll
        for (int bb = 0; bb < 4; ++bb)
            part[ih][bb][n] = make_float2(num[bb], den[bb]);
        __syncthreads();
        // reduce for this thread's (bb=ih, n)
        float wn = sens_n, wd = sens_d;
#pragma unroll
        for (int s2 = 0; s2 < 4; ++s2) {
            float2 v = part[s2][ih][n];
            wn += v.x;
            wd += v.y;
        }
        float res = (c * vp + gvl + wn) * RCPF(c + g + wd);
        vp = res;
        if (s == UNFOLDS - 1)
            out[(b0 + ih) * Nn + n] = res;       // coalesced final store
        else
            ((float*)vt)[n * 4 + ih] = res;
    }
}

// ---------------------------------------------------------------------------
extern "C" void kernel_launch(void* const* d_in, const int* in_sizes, int n_in,
                              void* d_out, int out_size, void* d_ws, size_t ws_size,
                              hipStream_t stream) {
    const float* inputs   = (const float*)d_in[0];
    const float* state    = (const float*)d_in[1];
    const float* input_w  = (const float*)d_in[2];
    const float* input_b  = (const float*)d_in[3];
    const float* smu      = (const float*)d_in[4];
    const float* ssigma   = (const float*)d_in[5];
    const float* sW       = (const float*)d_in[6];
    const float* serev    = (const float*)d_in[7];
    const float* mu       = (const float*)d_in[8];
    const float* sigma    = (const float*)d_in[9];
    const float* W        = (const float*)d_in[10];
    const float* erev     = (const float*)d_in[11];
    const float* vleak    = (const float*)d_in[12];
    const float* gleak    = (const float*)d_in[13];
    const float* cmt      = (const float*)d_in[14];
    float* out = (float*)d_out;

    // Workspace: Prec 1 MiB | Psen 512 KiB
    char* ws = (char*)d_ws;
    float4* Prec = (float4*)ws;
    float4* Psen = (float4*)(ws + (1u << 20));

    pack_kernel<<<(Nn * Nn + In * Nn + 255) / 256, 256, 0, stream>>>(
        mu, sigma, W, erev, smu, ssigma, sW, serev, Prec, Psen);

    ltc_fused_kernel<<<Bn / 4, 1024, 0, stream>>>(
        inputs, state, input_w, input_b, Psen, Prec, vleak, gleak, cmt, out);
}